// Round 3
// baseline (34.097 us; speedup 1.0000x reference)
//
#include <hip/hip_runtime.h>

// SpecAugment: x[B,1,F,T] fp32; zero freq band [f0,f0+f) and time band [t0,t0+t) per batch.
// B=64, F=128, T=3000. Memory-bound masked copy.
// Grid = (F, B): one block per (freq-row, batch). All mask params block-uniform
// -> scalar loads, no per-element divides; freq-masked rows skip the read.
// Native ext_vector float4 so __builtin_nontemporal_store accepts it.

typedef float v4f __attribute__((ext_vector_type(4)));

constexpr int F_  = 128;
constexpr int T4  = 750;   // 3000 / 4 float4 per row

__global__ void __launch_bounds__(256)
specaug_kernel(const v4f* __restrict__ x,
               const int* __restrict__ t,
               const int* __restrict__ f,
               const int* __restrict__ t0,
               const int* __restrict__ f0,
               v4f* __restrict__ out) {
    const int fr = blockIdx.x;   // 0..127  freq row
    const int b  = blockIdx.y;   // 0..63   batch

    // Block-uniform mask params (compiler emits scalar loads).
    const int fb   = f0[b];
    const int flen = f[b];
    const int tb   = t0[b];
    const int tlen = t[b];

    const size_t row = (size_t)(b * F_ + fr) * T4;
    const v4f* __restrict__ src = x + row;
    v4f* __restrict__ dst = out + row;

    if ((unsigned)(fr - fb) < (unsigned)flen) {
        // whole row zeroed: skip the load entirely
        const v4f z = (v4f)(0.f);
        for (int j = threadIdx.x; j < T4; j += 256) {
            __builtin_nontemporal_store(z, &dst[j]);
        }
    } else {
        for (int j = threadIdx.x; j < T4; j += 256) {
            v4f v = src[j];
            const int tt = j * 4;
            if ((unsigned)(tt + 0 - tb) < (unsigned)tlen) v.x = 0.f;
            if ((unsigned)(tt + 1 - tb) < (unsigned)tlen) v.y = 0.f;
            if ((unsigned)(tt + 2 - tb) < (unsigned)tlen) v.z = 0.f;
            if ((unsigned)(tt + 3 - tb) < (unsigned)tlen) v.w = 0.f;
            __builtin_nontemporal_store(v, &dst[j]);
        }
    }
}

extern "C" void kernel_launch(void* const* d_in, const int* in_sizes, int n_in,
                              void* d_out, int out_size, void* d_ws, size_t ws_size,
                              hipStream_t stream) {
    const v4f* x  = (const v4f*)d_in[0];
    const int* t  = (const int*)d_in[1];
    const int* f  = (const int*)d_in[2];
    const int* t0 = (const int*)d_in[3];
    const int* f0 = (const int*)d_in[4];
    v4f* out      = (v4f*)d_out;

    dim3 grid(F_, 64);
    specaug_kernel<<<grid, 256, 0, stream>>>(x, t, f, t0, f0, out);
}